// Round 1
// baseline (665.090 us; speedup 1.0000x reference)
//
#include <hip/hip_runtime.h>
#include <math.h>

// StreamingTransformerLayer on MI355X (gfx950).
// B=8 T=256 C=2048 H=16 Dh=128 CAP=2048 FF=8192, offset read on-device.
// Pipeline: rmsnorm -> qkv GEMM (bf16 mfma) -> rope/split -> flash attn
//           -> out-proj GEMM(+res -> d_out) -> rmsnorm -> fc1+gelu -> fc2(+res).

typedef __bf16 bf16_t;
typedef __bf16 bf16x8 __attribute__((ext_vector_type(8)));
typedef __bf16 bf16x4 __attribute__((ext_vector_type(4)));
typedef float  f32x4  __attribute__((ext_vector_type(4)));

#define MFMA(a, b, c) __builtin_amdgcn_mfma_f32_16x16x32_bf16((a), (b), (c), 0, 0, 0)

static __device__ __forceinline__ bf16x8 cvt8(const float* __restrict__ src) {
    f32x4 f0 = *(const f32x4*)src;
    f32x4 f1 = *(const f32x4*)(src + 4);
    bf16x8 v;
    v[0] = (bf16_t)f0[0]; v[1] = (bf16_t)f0[1]; v[2] = (bf16_t)f0[2]; v[3] = (bf16_t)f0[3];
    v[4] = (bf16_t)f1[0]; v[5] = (bf16_t)f1[1]; v[6] = (bf16_t)f1[2]; v[7] = (bf16_t)f1[3];
    return v;
}

// ---------------- RMSNorm: one block per row of 2048 f32, out bf16 ----------------
__global__ __launch_bounds__(256)
void rmsnorm_kernel(const float* __restrict__ x, const float* __restrict__ alpha,
                    bf16_t* __restrict__ out)
{
    const int C = 2048;
    const int row = blockIdx.x;
    const int tid = threadIdx.x;
    const float* xr = x + (size_t)row * C;
    f32x4 a0 = *(const f32x4*)&xr[tid * 8];
    f32x4 a1 = *(const f32x4*)&xr[tid * 8 + 4];
    float ss = a0[0]*a0[0] + a0[1]*a0[1] + a0[2]*a0[2] + a0[3]*a0[3]
             + a1[0]*a1[0] + a1[1]*a1[1] + a1[2]*a1[2] + a1[3]*a1[3];
    #pragma unroll
    for (int d = 32; d >= 1; d >>= 1) ss += __shfl_xor(ss, d);
    __shared__ float red[4];
    const int lane = tid & 63, wid = tid >> 6;
    if (lane == 0) red[wid] = ss;
    __syncthreads();
    const float tot = red[0] + red[1] + red[2] + red[3];
    const float rs = rsqrtf(1e-5f + tot * (1.0f / C));
    f32x4 l0 = *(const f32x4*)&alpha[tid * 8];
    f32x4 l1 = *(const f32x4*)&alpha[tid * 8 + 4];
    bf16x8 o8;
    o8[0] = (bf16_t)(a0[0] * l0[0] * rs); o8[1] = (bf16_t)(a0[1] * l0[1] * rs);
    o8[2] = (bf16_t)(a0[2] * l0[2] * rs); o8[3] = (bf16_t)(a0[3] * l0[3] * rs);
    o8[4] = (bf16_t)(a1[0] * l1[0] * rs); o8[5] = (bf16_t)(a1[1] * l1[1] * rs);
    o8[6] = (bf16_t)(a1[2] * l1[2] * rs); o8[7] = (bf16_t)(a1[3] * l1[3] * rs);
    *(bf16x8*)&out[(size_t)row * C + tid * 8] = o8;
}

// ---------------- GEMM: C[M,N] = A[M,K](bf16) * Bw[N,K]^T (f32, cvt on stage) ----------------
// EPI: 0 f32 store | 1 res+acc f32 store | 2 gelu bf16 store | 3 bf16 store
template<int EPI>
__global__ __launch_bounds__(256)
void gemm_bt(const bf16_t* __restrict__ A, const float* __restrict__ Bw,
             float* Cf, bf16_t* Cb, const float* res,
             int M, int N, int K)
{
    __shared__ bf16_t As[128][72];   // +8 pad: 2-way-only bank conflicts
    __shared__ bf16_t Bs[128][72];
    const int m0 = blockIdx.y * 128, n0 = blockIdx.x * 128;
    const int tid = threadIdx.x;
    const int lane = tid & 63, wid = tid >> 6;
    const int wr = wid >> 1, wc = wid & 1;
    const int lr = lane & 15, lg = lane >> 4;
    f32x4 acc[4][4] = {};

    for (int kt = 0; kt < K; kt += 64) {
        __syncthreads();
        #pragma unroll
        for (int it = 0; it < 4; ++it) {
            const int idx = tid + it * 256;          // 128 rows x 8 col-groups
            const int r = idx >> 3, c8 = idx & 7;
            *(bf16x8*)&As[r][c8 * 8] = *(const bf16x8*)&A[(size_t)(m0 + r) * K + kt + c8 * 8];
        }
        #pragma unroll
        for (int it = 0; it < 4; ++it) {
            const int idx = tid + it * 256;
            const int r = idx >> 3, c8 = idx & 7;
            *(bf16x8*)&Bs[r][c8 * 8] = cvt8(&Bw[(size_t)(n0 + r) * K + kt + c8 * 8]);
        }
        __syncthreads();
        #pragma unroll
        for (int kk = 0; kk < 2; ++kk) {
            bf16x8 af[4], bfr[4];
            #pragma unroll
            for (int m = 0; m < 4; ++m)
                af[m] = *(const bf16x8*)&As[wr * 64 + m * 16 + lr][kk * 32 + lg * 8];
            #pragma unroll
            for (int n = 0; n < 4; ++n)
                bfr[n] = *(const bf16x8*)&Bs[wc * 64 + n * 16 + lr][kk * 32 + lg * 8];
            #pragma unroll
            for (int m = 0; m < 4; ++m)
                #pragma unroll
                for (int n = 0; n < 4; ++n)
                    acc[m][n] = MFMA(af[m], bfr[n], acc[m][n]);
        }
    }
    // epilogue; C/D frag: col=lane&15, row=(lane>>4)*4+reg (m89-verified)
    #pragma unroll
    for (int m = 0; m < 4; ++m) {
        #pragma unroll
        for (int n = 0; n < 4; ++n) {
            const int gmb = m0 + wr * 64 + m * 16 + lg * 4;
            const int gn  = n0 + wc * 64 + n * 16 + lr;
            #pragma unroll
            for (int r = 0; r < 4; ++r) {
                const size_t off = (size_t)(gmb + r) * N + gn;
                const float v = acc[m][n][r];
                if (EPI == 0)      Cf[off] = v;
                else if (EPI == 1) Cf[off] = res[off] + v;
                else if (EPI == 2) Cb[off] = (bf16_t)(0.5f * v * (1.0f + erff(v * 0.70710678118654752f)));
                else               Cb[off] = (bf16_t)v;
            }
        }
    }
}

// ---------------- RoPE + split qkv -> q/kn/vn in [B*H][T][Dh] bf16 ----------------
__global__ __launch_bounds__(256)
void rope_split_kernel(const bf16_t* __restrict__ qkv,
                       bf16_t* __restrict__ q, bf16_t* __restrict__ kn,
                       bf16_t* __restrict__ vn, const int* __restrict__ offp)
{
    const int m = blockIdx.x;            // b*T + t
    const int b = m >> 8, t = m & 255;
    const int tid = threadIdx.x;
    const int c = tid * 8;
    const int h = c >> 7, d0 = c & 127;
    const int pos = offp[0] + t;
    bf16x8 qv = *(const bf16x8*)&qkv[(size_t)m * 6144 + c];
    bf16x8 kv = *(const bf16x8*)&qkv[(size_t)m * 6144 + 2048 + c];
    bf16x8 vv = *(const bf16x8*)&qkv[(size_t)m * 6144 + 4096 + c];
    bf16x8 qo, ko;
    #pragma unroll
    for (int p = 0; p < 4; ++p) {
        const int i = (d0 >> 1) + p;                       // pair index, half=64
        const float ang = (float)pos * __expf(-(float)i * 0.14391156861538527f); // ln(1e4)/64
        const float sn = sinf(ang), cs = cosf(ang);
        const float q1 = (float)qv[2 * p], q2 = (float)qv[2 * p + 1];
        const float k1 = (float)kv[2 * p], k2 = (float)kv[2 * p + 1];
        qo[2 * p]     = (bf16_t)(q1 * cs - q2 * sn);
        qo[2 * p + 1] = (bf16_t)(q1 * sn + q2 * cs);
        ko[2 * p]     = (bf16_t)(k1 * cs - k2 * sn);
        ko[2 * p + 1] = (bf16_t)(k1 * sn + k2 * cs);
    }
    const size_t oi = (((size_t)(b * 16 + h) * 256) + t) * 128 + d0;
    *(bf16x8*)&q[oi]  = qo;
    *(bf16x8*)&kn[oi] = ko;
    *(bf16x8*)&vn[oi] = vv;
}

// ---------------- Flash attention: block = (b,h) x 128-row Q tile ----------------
__global__ __launch_bounds__(256)
void attn_kernel(const bf16_t* __restrict__ qh, const bf16_t* __restrict__ kn,
                 const bf16_t* __restrict__ vn, const float* __restrict__ kcache,
                 const float* __restrict__ vcache, bf16_t* __restrict__ outp,
                 const int* __restrict__ offp)
{
    const int T = 256, Dh = 128, CAP = 2048, H = 16;
    const float scale = 0.08838834764831845f;   // 1/sqrt(128)
    __shared__ bf16_t Ks[64][136];   // [s_local][d], +8 pad
    __shared__ bf16_t Vt[128][72];   // [d][s_local], +8 pad (write-conflict debt, see notes)
    __shared__ bf16_t Pl[4][32][72]; // per-wave P relayout buffer
    const int bh = blockIdx.x;
    const int t0 = blockIdx.y * 128;
    const int b = bh >> 4, h = bh & 15;
    const int offset = offp[0];
    const int Stot = offset + T;     // assumes offset+T <= CAP (holds for given inputs)
    const int tid = threadIdx.x, lane = tid & 63, wid = tid >> 6;
    const int lr = lane & 15, lg = lane >> 4;

    // Q fragments in registers: wave owns rows t0+wid*32 .. +31
    bf16x8 qf[2][4];
    {
        const bf16_t* qbase = qh + ((size_t)bh * T + t0 + wid * 32) * Dh;
        #pragma unroll
        for (int m = 0; m < 2; ++m)
            #pragma unroll
            for (int ks = 0; ks < 4; ++ks)
                qf[m][ks] = *(const bf16x8*)&qbase[(m * 16 + lr) * Dh + ks * 32 + lg * 8];
    }
    f32x4 accO[2][8] = {};
    float mrun[2][4], lrun[2][4];
    #pragma unroll
    for (int m = 0; m < 2; ++m)
        #pragma unroll
        for (int r = 0; r < 4; ++r) { mrun[m][r] = -3e38f; lrun[m][r] = 0.0f; }

    const int qpos_max = offset + t0 + 127;
    int smax = qpos_max + 1; if (smax > Stot) smax = Stot;
    const int nch = (smax + 63) >> 6;

    for (int ch = 0; ch < nch; ++ch) {
        const int s0 = ch * 64;
        __syncthreads();
        // stage K (row-major) and V (transposed) for this 64-key chunk
        #pragma unroll
        for (int it = 0; it < 4; ++it) {
            const int idx = tid + it * 256;          // 64 rows x 16 col-groups
            const int r = idx >> 4, c8 = idx & 15;
            const int s = s0 + r;
            bf16x8 kv8, vv8;
            if (s < offset) {
                const size_t base = (((size_t)b * H + h) * CAP + s) * Dh + c8 * 8;
                kv8 = cvt8(&kcache[base]);
                vv8 = cvt8(&vcache[base]);
            } else if (s < Stot) {
                const size_t base = ((size_t)bh * T + (s - offset)) * Dh + c8 * 8;
                kv8 = *(const bf16x8*)&kn[base];
                vv8 = *(const bf16x8*)&vn[base];
            } else {
                #pragma unroll
                for (int j = 0; j < 8; ++j) { kv8[j] = (bf16_t)0.0f; vv8[j] = (bf16_t)0.0f; }
            }
            *(bf16x8*)&Ks[r][c8 * 8] = kv8;
            #pragma unroll
            for (int j = 0; j < 8; ++j) Vt[c8 * 8 + j][r] = vv8[j];
        }
        __syncthreads();

        // QK^T: scores[t][s], A=Q frag, B=K frag (both 8-contig-K from row-major)
        f32x4 sc[2][4] = {};
        #pragma unroll
        for (int ks = 0; ks < 4; ++ks) {
            bf16x8 kf[4];
            #pragma unroll
            for (int n = 0; n < 4; ++n)
                kf[n] = *(const bf16x8*)&Ks[n * 16 + lr][ks * 32 + lg * 8];
            #pragma unroll
            for (int m = 0; m < 2; ++m)
                #pragma unroll
                for (int n = 0; n < 4; ++n)
                    sc[m][n] = MFMA(qf[m][ks], kf[n], sc[m][n]);
        }

        // mask + online softmax (rows live in 16-lane groups; shuffle-reduce over lr)
        #pragma unroll
        for (int m = 0; m < 2; ++m) {
            #pragma unroll
            for (int r = 0; r < 4; ++r) {
                const int qpos = offset + t0 + wid * 32 + m * 16 + lg * 4 + r;
                float mx = -3e38f;
                #pragma unroll
                for (int n = 0; n < 4; ++n) {
                    const int sabs = s0 + n * 16 + lr;
                    float v = sc[m][n][r] * scale;
                    v = (sabs <= qpos && sabs < Stot) ? v : -1e30f;
                    sc[m][n][r] = v;
                    mx = fmaxf(mx, v);
                }
                #pragma unroll
                for (int d = 8; d >= 1; d >>= 1) mx = fmaxf(mx, __shfl_xor(mx, d));
                const float mo = mrun[m][r];
                const float mn2 = fmaxf(mo, mx);
                const float al = __expf(mo - mn2);
                mrun[m][r] = mn2;
                lrun[m][r] *= al;
                #pragma unroll
                for (int df = 0; df < 8; ++df) accO[m][df][r] *= al;
                float rsum = 0.0f;
                #pragma unroll
                for (int n = 0; n < 4; ++n) {
                    const float p = __expf(sc[m][n][r] - mn2);
                    sc[m][n][r] = p;
                    rsum += p;
                }
                #pragma unroll
                for (int d = 8; d >= 1; d >>= 1) rsum += __shfl_xor(rsum, d);
                lrun[m][r] += rsum;
                #pragma unroll
                for (int n = 0; n < 4; ++n)
                    Pl[wid][m * 16 + lg * 4 + r][n * 16 + lr] = (bf16_t)sc[m][n][r];
            }
        }
        asm volatile("s_waitcnt lgkmcnt(0)" ::: "memory");  // P writes -> own-wave reads
        __builtin_amdgcn_sched_barrier(0);

        // PV: A = P (relayout via LDS), B = V^T frags (8-contig s)
        #pragma unroll
        for (int ks2 = 0; ks2 < 2; ++ks2) {
            bf16x8 pa[2];
            #pragma unroll
            for (int m = 0; m < 2; ++m)
                pa[m] = *(const bf16x8*)&Pl[wid][m * 16 + lr][ks2 * 32 + lg * 8];
            #pragma unroll
            for (int df = 0; df < 8; ++df) {
                const bf16x8 vb = *(const bf16x8*)&Vt[df * 16 + lr][ks2 * 32 + lg * 8];
                #pragma unroll
                for (int m = 0; m < 2; ++m)
                    accO[m][df] = MFMA(pa[m], vb, accO[m][df]);
            }
        }
    }

    // normalize + write o[b][t][h*128+d] bf16
    #pragma unroll
    for (int m = 0; m < 2; ++m) {
        float rinv[4];
        #pragma unroll
        for (int r = 0; r < 4; ++r) rinv[r] = 1.0f / lrun[m][r];
        #pragma unroll
        for (int df = 0; df < 8; ++df) {
            #pragma unroll
            for (int r = 0; r < 4; ++r) {
                const int t = t0 + wid * 32 + m * 16 + lg * 4 + r;
                outp[((size_t)b * T + t) * 2048 + h * 128 + df * 16 + lr] =
                    (bf16_t)(accO[m][df][r] * rinv[r]);
            }
        }
    }
}

// ---------------- launch ----------------
extern "C" void kernel_launch(void* const* d_in, const int* in_sizes, int n_in,
                              void* d_out, int out_size, void* d_ws, size_t ws_size,
                              hipStream_t stream)
{
    const float* x    = (const float*)d_in[0];
    const float* kc   = (const float*)d_in[1];
    const float* vc   = (const float*)d_in[2];
    const float* wqkv = (const float*)d_in[3];
    const float* wo   = (const float*)d_in[4];
    const float* a1   = (const float*)d_in[5];
    const float* a2   = (const float*)d_in[6];
    const float* w1   = (const float*)d_in[7];
    const float* w2   = (const float*)d_in[8];
    const int*   offp = (const int*)d_in[9];
    float* out = (float*)d_out;

    char* ws = (char*)d_ws;
    // region map (64 MiB total; h reuses xn, g reuses qkv+q which are dead by then)
    bf16_t* xn  = (bf16_t*)(ws + 0);                  // [2048][2048]
    bf16_t* qkv = (bf16_t*)(ws + (8ull  << 20));      // [2048][6144]
    bf16_t* q   = (bf16_t*)(ws + (32ull << 20));      // [128][256][128]
    bf16_t* kn  = (bf16_t*)(ws + (40ull << 20));
    bf16_t* vn  = (bf16_t*)(ws + (48ull << 20));
    bf16_t* o   = (bf16_t*)(ws + (56ull << 20));      // [2048][2048]
    bf16_t* hbuf = xn;                                // [2048][2048]
    bf16_t* g   = qkv;                                // [2048][8192]

    // 1. xn = rmsnorm(x, a1)
    rmsnorm_kernel<<<2048, 256, 0, stream>>>(x, a1, xn);
    // 2. qkv = xn @ wqkv^T   (bf16 out)
    gemm_bt<3><<<dim3(48, 16), 256, 0, stream>>>(xn, wqkv, nullptr, qkv, nullptr, 2048, 6144, 2048);
    // 3. rope + split
    rope_split_kernel<<<2048, 256, 0, stream>>>(qkv, q, kn, vn, offp);
    // 4. attention -> o (bf16, [B,T,C])
    attn_kernel<<<dim3(128, 2), 256, 0, stream>>>(q, kn, vn, kc, vc, o, offp);
    // 5. d_out = x + o @ wo^T   (f32; d_out doubles as x2)
    gemm_bt<1><<<dim3(16, 16), 256, 0, stream>>>(o, wo, out, nullptr, x, 2048, 2048, 2048);
    // 6. h = rmsnorm(d_out, a2)
    rmsnorm_kernel<<<2048, 256, 0, stream>>>(out, a2, hbuf);
    // 7. g = gelu(h @ w1^T)   (bf16 out)
    gemm_bt<2><<<dim3(64, 16), 256, 0, stream>>>(hbuf, w1, nullptr, g, nullptr, 2048, 8192, 2048);
    // 8. d_out = d_out + g @ w2^T
    gemm_bt<1><<<dim3(16, 16), 256, 0, stream>>>(g, w2, out, nullptr, out, 2048, 2048, 8192);
}

// Round 3
// 663.111 us; speedup vs baseline: 1.0030x; 1.0030x over previous
//
#include <hip/hip_runtime.h>
#include <math.h>

// StreamingTransformerLayer on MI355X (gfx950).  Round 2 (resubmit; infra flake).
// B=8 T=256 C=2048 H=16 Dh=128 CAP=2048 FF=8192, offset read on-device.
// Changes vs R1: all weights pre-converted f32->bf16 (one streamed pass),
// GEMMs rebuilt as m97 structure: 128x128 tile, BK=64, linear LDS,
// global_load_lds dwordx4 staging, XCD-aware block swizzle.
// FF runs as two FF/2 passes to keep ws usage <= 56 MiB.

typedef __bf16 bf16_t;
typedef __bf16 bf16x8 __attribute__((ext_vector_type(8)));
typedef float  f32x4  __attribute__((ext_vector_type(4)));

#define MFMA(a, b, c) __builtin_amdgcn_mfma_f32_16x16x32_bf16((a), (b), (c), 0, 0, 0)

static __device__ __forceinline__ bf16x8 cvt8(const float* __restrict__ src) {
    f32x4 f0 = *(const f32x4*)src;
    f32x4 f1 = *(const f32x4*)(src + 4);
    bf16x8 v;
    v[0] = (bf16_t)f0[0]; v[1] = (bf16_t)f0[1]; v[2] = (bf16_t)f0[2]; v[3] = (bf16_t)f0[3];
    v[4] = (bf16_t)f1[0]; v[5] = (bf16_t)f1[1]; v[6] = (bf16_t)f1[2]; v[7] = (bf16_t)f1[3];
    return v;
}

// async global->LDS, 16B per lane; lds base must be wave-uniform
static __device__ __forceinline__ void gload16(const bf16_t* g, bf16_t* lds) {
    __builtin_amdgcn_global_load_lds(
        (const __attribute__((address_space(1))) void*)g,
        (__attribute__((address_space(3))) void*)lds, 16, 0, 0);
}

// ---------------- weight convert: rows x cols, row stride (f32 -> bf16) ----------------
__global__ __launch_bounds__(256)
void cvt_rows_kernel(const float* __restrict__ src, bf16_t* __restrict__ dst,
                     int cols, int src_stride)
{
    const int row = blockIdx.x;
    const float* s = src + (size_t)row * src_stride;
    bf16_t* d = dst + (size_t)row * cols;
    for (int c = threadIdx.x * 8; c < cols; c += blockDim.x * 8)
        *(bf16x8*)&d[c] = cvt8(&s[c]);
}

// ---------------- RMSNorm: one block per row of 2048 f32, out bf16 ----------------
__global__ __launch_bounds__(256)
void rmsnorm_kernel(const float* __restrict__ x, const float* __restrict__ alpha,
                    bf16_t* __restrict__ out)
{
    const int C = 2048;
    const int row = blockIdx.x;
    const int tid = threadIdx.x;
    const float* xr = x + (size_t)row * C;
    f32x4 a0 = *(const f32x4*)&xr[tid * 8];
    f32x4 a1 = *(const f32x4*)&xr[tid * 8 + 4];
    float ss = a0[0]*a0[0] + a0[1]*a0[1] + a0[2]*a0[2] + a0[3]*a0[3]
             + a1[0]*a1[0] + a1[1]*a1[1] + a1[2]*a1[2] + a1[3]*a1[3];
    #pragma unroll
    for (int d = 32; d >= 1; d >>= 1) ss += __shfl_xor(ss, d);
    __shared__ float red[4];
    const int lane = tid & 63, wid = tid >> 6;
    if (lane == 0) red[wid] = ss;
    __syncthreads();
    const float tot = red[0] + red[1] + red[2] + red[3];
    const float rs = rsqrtf(1e-5f + tot * (1.0f / C));
    f32x4 l0 = *(const f32x4*)&alpha[tid * 8];
    f32x4 l1 = *(const f32x4*)&alpha[tid * 8 + 4];
    bf16x8 o8;
    o8[0] = (bf16_t)(a0[0] * l0[0] * rs); o8[1] = (bf16_t)(a0[1] * l0[1] * rs);
    o8[2] = (bf16_t)(a0[2] * l0[2] * rs); o8[3] = (bf16_t)(a0[3] * l0[3] * rs);
    o8[4] = (bf16_t)(a1[0] * l1[0] * rs); o8[5] = (bf16_t)(a1[1] * l1[1] * rs);
    o8[6] = (bf16_t)(a1[2] * l1[2] * rs); o8[7] = (bf16_t)(a1[3] * l1[3] * rs);
    *(bf16x8*)&out[(size_t)row * C + tid * 8] = o8;
}

// ---------------- GEMM (m97 structure): C[M,N] = A[M,K] * B[N,K]^T, both bf16 ----------------
// 128x128 tile, BK=64, linear LDS, global_load_lds x16, 4 waves of 64x64.
// EPI: 0 f32 | 1 res+acc f32 | 2 gelu bf16 | 3 bf16
template<int EPI>
__global__ __launch_bounds__(256)
void gemm_bb(const bf16_t* __restrict__ A, const bf16_t* __restrict__ B,
             float* Cf, bf16_t* Cb, const float* __restrict__ res,
             int M, int N, int K)
{
    __shared__ bf16_t As[128 * 64];
    __shared__ bf16_t Bs[128 * 64];
    // XCD-aware swizzle of flat block id (grids launched with nwg % 8 == 0)
    const int gx = gridDim.x;
    const int nwg = gx * gridDim.y;
    int bid = blockIdx.y * gx + blockIdx.x;
    bid = (bid & 7) * (nwg >> 3) + (bid >> 3);
    const int n0 = (bid % gx) * 128;
    const int m0 = (bid / gx) * 128;

    const int tid = threadIdx.x;
    const int lane = tid & 63, wid = tid >> 6;
    const int wr = wid >> 1, wc = wid & 1;
    const int lr = lane & 15, lg = lane >> 4;
    const int srow = lane >> 3;          // staging: lane's row within 8-row group
    const int scol = (lane & 7) * 8;     // staging: lane's col (8 bf16 = 16B)
    f32x4 acc[4][4] = {};

    for (int kt = 0; kt < K; kt += 64) {
        __syncthreads();                 // prior compute done before overwrite
        #pragma unroll
        for (int it = 0; it < 4; ++it) { // wave stages rows [wid*32, wid*32+32)
            const int r = wid * 32 + it * 8;
            gload16(&A[(size_t)(m0 + r + srow) * K + kt + scol], &As[r * 64]);
            gload16(&B[(size_t)(n0 + r + srow) * K + kt + scol], &Bs[r * 64]);
        }
        __syncthreads();                 // compiler drains vmcnt before barrier
        #pragma unroll
        for (int kk = 0; kk < 2; ++kk) {
            bf16x8 af[4], bfr[4];
            #pragma unroll
            for (int m = 0; m < 4; ++m)
                af[m] = *(const bf16x8*)&As[(wr * 64 + m * 16 + lr) * 64 + kk * 32 + lg * 8];
            #pragma unroll
            for (int n = 0; n < 4; ++n)
                bfr[n] = *(const bf16x8*)&Bs[(wc * 64 + n * 16 + lr) * 64 + kk * 32 + lg * 8];
            #pragma unroll
            for (int m = 0; m < 4; ++m)
                #pragma unroll
                for (int n = 0; n < 4; ++n)
                    acc[m][n] = MFMA(af[m], bfr[n], acc[m][n]);
        }
    }
    // epilogue; C/D frag: col=lane&15, row=(lane>>4)*4+reg (m89-verified)
    #pragma unroll
    for (int m = 0; m < 4; ++m) {
        #pragma unroll
        for (int n = 0; n < 4; ++n) {
            const int gmb = m0 + wr * 64 + m * 16 + lg * 4;
            const int gn  = n0 + wc * 64 + n * 16 + lr;
            #pragma unroll
            for (int r = 0; r < 4; ++r) {
                const size_t off = (size_t)(gmb + r) * N + gn;
                const float v = acc[m][n][r];
                if (EPI == 0)      Cf[off] = v;
                else if (EPI == 1) Cf[off] = res[off] + v;
                else if (EPI == 2) Cb[off] = (bf16_t)(0.5f * v * (1.0f + erff(v * 0.70710678118654752f)));
                else               Cb[off] = (bf16_t)v;
            }
        }
    }
}

// ---------------- RoPE + split qkv -> q/kn/vn in [B*H][T][Dh] bf16 ----------------
__global__ __launch_bounds__(256)
void rope_split_kernel(const bf16_t* __restrict__ qkv,
                       bf16_t* __restrict__ q, bf16_t* __restrict__ kn,
                       bf16_t* __restrict__ vn, const int* __restrict__ offp)
{
    const int m = blockIdx.x;            // b*T + t
    const int b = m >> 8, t = m & 255;
    const int tid = threadIdx.x;
    const int c = tid * 8;
    const int h = c >> 7, d0 = c & 127;
    const int pos = offp[0] + t;
    bf16x8 qv = *(const bf16x8*)&qkv[(size_t)m * 6144 + c];
    bf16x8 kv = *(const bf16x8*)&qkv[(size_t)m * 6144 + 2048 + c];
    bf16x8 vv = *(const bf16x8*)&qkv[(size_t)m * 6144 + 4096 + c];
    bf16x8 qo, ko;
    #pragma unroll
    for (int p = 0; p < 4; ++p) {
        const int i = (d0 >> 1) + p;                       // pair index, half=64
        const float ang = (float)pos * __expf(-(float)i * 0.14391156861538527f); // ln(1e4)/64
        const float sn = sinf(ang), cs = cosf(ang);
        const float q1 = (float)qv[2 * p], q2 = (float)qv[2 * p + 1];
        const float k1 = (float)kv[2 * p], k2 = (float)kv[2 * p + 1];
        qo[2 * p]     = (bf16_t)(q1 * cs - q2 * sn);
        qo[2 * p + 1] = (bf16_t)(q1 * sn + q2 * cs);
        ko[2 * p]     = (bf16_t)(k1 * cs - k2 * sn);
        ko[2 * p + 1] = (bf16_t)(k1 * sn + k2 * cs);
    }
    const size_t oi = (((size_t)(b * 16 + h) * 256) + t) * 128 + d0;
    *(bf16x8*)&q[oi]  = qo;
    *(bf16x8*)&kn[oi] = ko;
    *(bf16x8*)&vn[oi] = vv;
}

// ---------------- Flash attention: block = (b,h) x 128-row Q tile ----------------
__global__ __launch_bounds__(256)
void attn_kernel(const bf16_t* __restrict__ qh, const bf16_t* __restrict__ kn,
                 const bf16_t* __restrict__ vn, const float* __restrict__ kcache,
                 const float* __restrict__ vcache, bf16_t* __restrict__ outp,
                 const int* __restrict__ offp)
{
    const int T = 256, Dh = 128, CAP = 2048, H = 16;
    const float scale = 0.08838834764831845f;   // 1/sqrt(128)
    __shared__ bf16_t Ks[64][136];   // [s_local][d], +8 pad
    __shared__ bf16_t Vt[128][72];   // [d][s_local], +8 pad
    __shared__ bf16_t Pl[4][32][72]; // per-wave P relayout buffer
    const int bh = blockIdx.x;
    const int t0 = blockIdx.y * 128;
    const int b = bh >> 4, h = bh & 15;
    const int offset = offp[0];
    const int Stot = offset + T;     // assumes offset+T <= CAP (holds for given inputs)
    const int tid = threadIdx.x, lane = tid & 63, wid = tid >> 6;
    const int lr = lane & 15, lg = lane >> 4;

    bf16x8 qf[2][4];
    {
        const bf16_t* qbase = qh + ((size_t)bh * T + t0 + wid * 32) * Dh;
        #pragma unroll
        for (int m = 0; m < 2; ++m)
            #pragma unroll
            for (int ks = 0; ks < 4; ++ks)
                qf[m][ks] = *(const bf16x8*)&qbase[(m * 16 + lr) * Dh + ks * 32 + lg * 8];
    }
    f32x4 accO[2][8] = {};
    float mrun[2][4], lrun[2][4];
    #pragma unroll
    for (int m = 0; m < 2; ++m)
        #pragma unroll
        for (int r = 0; r < 4; ++r) { mrun[m][r] = -3e38f; lrun[m][r] = 0.0f; }

    const int qpos_max = offset + t0 + 127;
    int smax = qpos_max + 1; if (smax > Stot) smax = Stot;
    const int nch = (smax + 63) >> 6;

    for (int ch = 0; ch < nch; ++ch) {
        const int s0 = ch * 64;
        __syncthreads();
        #pragma unroll
        for (int it = 0; it < 4; ++it) {
            const int idx = tid + it * 256;          // 64 rows x 16 col-groups
            const int r = idx >> 4, c8 = idx & 15;
            const int s = s0 + r;
            bf16x8 kv8, vv8;
            if (s < offset) {
                const size_t base = (((size_t)b * H + h) * CAP + s) * Dh + c8 * 8;
                kv8 = cvt8(&kcache[base]);
                vv8 = cvt8(&vcache[base]);
            } else if (s < Stot) {
                const size_t base = ((size_t)bh * T + (s - offset)) * Dh + c8 * 8;
                kv8 = *(const bf16x8*)&kn[base];
                vv8 = *(const bf16x8*)&vn[base];
            } else {
                #pragma unroll
                for (int j = 0; j < 8; ++j) { kv8[j] = (bf16_t)0.0f; vv8[j] = (bf16_t)0.0f; }
            }
            *(bf16x8*)&Ks[r][c8 * 8] = kv8;
            #pragma unroll
            for (int j = 0; j < 8; ++j) Vt[c8 * 8 + j][r] = vv8[j];
        }
        __syncthreads();

        f32x4 sc[2][4] = {};
        #pragma unroll
        for (int ks = 0; ks < 4; ++ks) {
            bf16x8 kf[4];
            #pragma unroll
            for (int n = 0; n < 4; ++n)
                kf[n] = *(const bf16x8*)&Ks[n * 16 + lr][ks * 32 + lg * 8];
            #pragma unroll
            for (int m = 0; m < 2; ++m)
                #pragma unroll
                for (int n = 0; n < 4; ++n)
                    sc[m][n] = MFMA(qf[m][ks], kf[n], sc[m][n]);
        }

        #pragma unroll
        for (int m = 0; m < 2; ++m) {
            #pragma unroll
            for (int r = 0; r < 4; ++r) {
                const int qpos = offset + t0 + wid * 32 + m * 16 + lg * 4 + r;
                float mx = -3e38f;
                #pragma unroll
                for (int n = 0; n < 4; ++n) {
                    const int sabs = s0 + n * 16 + lr;
                    float v = sc[m][n][r] * scale;
                    v = (sabs <= qpos && sabs < Stot) ? v : -1e30f;
                    sc[m][n][r] = v;
                    mx = fmaxf(mx, v);
                }
                #pragma unroll
                for (int d = 8; d >= 1; d >>= 1) mx = fmaxf(mx, __shfl_xor(mx, d));
                const float mo = mrun[m][r];
                const float mn2 = fmaxf(mo, mx);
                const float al = __expf(mo - mn2);
                mrun[m][r] = mn2;
                lrun[m][r] *= al;
                #pragma unroll
                for (int df = 0; df < 8; ++df) accO[m][df][r] *= al;
                float rsum = 0.0f;
                #pragma unroll
                for (int n = 0; n < 4; ++n) {
                    const float p = __expf(sc[m][n][r] - mn2);
                    sc[m][n][r] = p;
                    rsum += p;
                }
                #pragma unroll
                for (int d = 8; d >= 1; d >>= 1) rsum += __shfl_xor(rsum, d);
                lrun[m][r] += rsum;
                #pragma unroll
                for (int n = 0; n < 4; ++n)
                    Pl[wid][m * 16 + lg * 4 + r][n * 16 + lr] = (bf16_t)sc[m][n][r];
            }
        }
        asm volatile("s_waitcnt lgkmcnt(0)" ::: "memory");
        __builtin_amdgcn_sched_barrier(0);

        #pragma unroll
        for (int ks2 = 0; ks2 < 2; ++ks2) {
            bf16x8 pa[2];
            #pragma unroll
            for (int m = 0; m < 2; ++m)
                pa[m] = *(const bf16x8*)&Pl[wid][m * 16 + lr][ks2 * 32 + lg * 8];
            #pragma unroll
            for (int df = 0; df < 8; ++df) {
                const bf16x8 vb = *(const bf16x8*)&Vt[df * 16 + lr][ks2 * 32 + lg * 8];
                #pragma unroll
                for (int m = 0; m < 2; ++m)
                    accO[m][df] = MFMA(pa[m], vb, accO[m][df]);
            }
        }
    }

    #pragma unroll
    for (int m = 0; m < 2; ++m) {
        float rinv[4];
        #pragma unroll
        for (int r = 0; r < 4; ++r) rinv[r] = 1.0f / lrun[m][r];
        #pragma unroll
        for (int df = 0; df < 8; ++df) {
            #pragma unroll
            for (int r = 0; r < 4; ++r) {
                const int t = t0 + wid * 32 + m * 16 + lg * 4 + r;
                outp[((size_t)b * T + t) * 2048 + h * 128 + df * 16 + lr] =
                    (bf16_t)(accO[m][df][r] * rinv[r]);
            }
        }
    }
}

// ---------------- launch ----------------
extern "C" void kernel_launch(void* const* d_in, const int* in_sizes, int n_in,
                              void* d_out, int out_size, void* d_ws, size_t ws_size,
                              hipStream_t stream)
{
    const float* x    = (const float*)d_in[0];
    const float* kc   = (const float*)d_in[1];
    const float* vc   = (const float*)d_in[2];
    const float* wqkv = (const float*)d_in[3];
    const float* wo   = (const float*)d_in[4];
    const float* a1   = (const float*)d_in[5];
    const float* a2   = (const float*)d_in[6];
    const float* w1   = (const float*)d_in[7];
    const float* w2   = (const float*)d_in[8];
    const int*   offp = (const int*)d_in[9];
    float* out = (float*)d_out;

    char* ws = (char*)d_ws;
    // region map, peak 56 MiB (within proven-safe 64 MiB):
    // phase A: xn[0,8) wqkv_b[8,32) qkv[32,56)
    // phase B: q/kn/vn[8,32) wo_b[32,40) o[40,48)
    // phase C: hbuf[0,8) w1b[8,24) g_h[24,40) w2b[40,56)
    bf16_t* xn     = (bf16_t*)(ws + 0);
    bf16_t* wqkv_b = (bf16_t*)(ws + (8ull  << 20));
    bf16_t* qkv    = (bf16_t*)(ws + (32ull << 20));
    bf16_t* q      = (bf16_t*)(ws + (8ull  << 20));
    bf16_t* kn     = (bf16_t*)(ws + (16ull << 20));
    bf16_t* vn     = (bf16_t*)(ws + (24ull << 20));
    bf16_t* wo_b   = (bf16_t*)(ws + (32ull << 20));
    bf16_t* o      = (bf16_t*)(ws + (40ull << 20));
    bf16_t* hbuf   = (bf16_t*)(ws + 0);
    bf16_t* w1b    = (bf16_t*)(ws + (8ull  << 20));
    bf16_t* g_h    = (bf16_t*)(ws + (24ull << 20));
    bf16_t* w2b    = (bf16_t*)(ws + (40ull << 20));

    // 1. xn = rmsnorm(x, a1); convert wqkv
    rmsnorm_kernel<<<2048, 256, 0, stream>>>(x, a1, xn);
    cvt_rows_kernel<<<6144, 256, 0, stream>>>(wqkv, wqkv_b, 2048, 2048);
    // 2. qkv = xn @ wqkv^T (bf16)
    gemm_bb<3><<<dim3(48, 16), 256, 0, stream>>>(xn, wqkv_b, nullptr, qkv, nullptr, 2048, 6144, 2048);
    // 3. rope + split; convert wo
    rope_split_kernel<<<2048, 256, 0, stream>>>(qkv, q, kn, vn, offp);
    cvt_rows_kernel<<<2048, 256, 0, stream>>>(wo, wo_b, 2048, 2048);
    // 4. attention -> o (bf16 [B,T,C])
    attn_kernel<<<dim3(128, 2), 256, 0, stream>>>(q, kn, vn, kc, vc, o, offp);
    // 5. d_out = x + o @ wo^T
    gemm_bb<1><<<dim3(16, 16), 256, 0, stream>>>(o, wo_b, out, nullptr, x, 2048, 2048, 2048);
    // 6. hbuf = rmsnorm(d_out, a2)
    rmsnorm_kernel<<<2048, 256, 0, stream>>>(out, a2, hbuf);
    // 7-8. FF in two FF/2 passes: g_h = gelu(hbuf @ w1h^T); d_out += g_h @ w2h^T
    for (int hh = 0; hh < 2; ++hh) {
        cvt_rows_kernel<<<4096, 256, 0, stream>>>(w1 + (size_t)hh * 4096 * 2048, w1b, 2048, 2048);
        gemm_bb<2><<<dim3(32, 16), 256, 0, stream>>>(hbuf, w1b, nullptr, g_h, nullptr, 2048, 4096, 2048);
        cvt_rows_kernel<<<2048, 256, 0, stream>>>(w2 + (size_t)hh * 4096, w2b, 4096, 8192);
        gemm_bb<1><<<dim3(16, 16), 256, 0, stream>>>(g_h, w2b, out, nullptr, out, 2048, 2048, 4096);
    }
}